// Round 1
// baseline (17.033 us; speedup 1.0000x reference)
//
#include <hip/hip_runtime.h>
#include <hip/hip_bf16.h>

// Problem: N=32, T=5, V=64, F=512, t_mid = 2
// xm = x[:, 2, :, :]                         (32, 64, 512)
// tmpS[n,i,j] = exp( sum_f |xm[n,i,f]-xm[n,j,f]| * a[f] )   (symmetric in i,j)
// colsum[n,i] = sum_k tmpS[n,k,i] == sum_k tmpS[n,i,k]  (by symmetry -> row-local)
// S[n,i,j] = tmpS[n,i,j] / colsum[n,i]
//
// One block per (n,i) row: 256 threads = 64 j-groups x 4 f-partitions.

#define NN 32
#define TT 5
#define VV 64
#define FF 512
#define TMID 2

__global__ __launch_bounds__(256) void pairsim_kernel(
    const float* __restrict__ x, const float* __restrict__ a,
    float* __restrict__ out) {
  const int b = blockIdx.x;      // 0 .. N*V-1
  const int n = b >> 6;          // b / 64
  const int i = b & 63;
  const int t = threadIdx.x;     // 0 .. 255

  __shared__ float xi[FF];       // row i of xm[n]
  __shared__ float av[FF];       // the weight vector a
  __shared__ float red[VV];      // exp values per j

  const float* xm = x + ((size_t)n * TT + TMID) * (size_t)VV * FF;

  // Stage xi and a into LDS (fully coalesced float4 loads).
  if (t < 128) {
    float4 v = reinterpret_cast<const float4*>(xm + (size_t)i * FF)[t];
    reinterpret_cast<float4*>(xi)[t] = v;
  } else {
    float4 v = reinterpret_cast<const float4*>(a)[t - 128];
    reinterpret_cast<float4*>(av)[t - 128] = v;
  }
  __syncthreads();

  const int j = t >> 2;          // 0..63
  const int part = t & 3;        // 0..3
  const float* xj = xm + (size_t)j * FF;

  float acc = 0.f;
#pragma unroll
  for (int k = 0; k < 32; ++k) {
    const int f = k * 16 + part * 4;   // each 4-lane group covers contiguous 64B
    float4 vj = *reinterpret_cast<const float4*>(xj + f);
    float4 vi = *reinterpret_cast<const float4*>(xi + f);
    float4 va = *reinterpret_cast<const float4*>(av + f);
    acc += fabsf(vi.x - vj.x) * va.x;
    acc += fabsf(vi.y - vj.y) * va.y;
    acc += fabsf(vi.z - vj.z) * va.z;
    acc += fabsf(vi.w - vj.w) * va.w;
  }
  // Fold the 4 f-partitions (lanes j*4 .. j*4+3).
  acc += __shfl_xor(acc, 1);
  acc += __shfl_xor(acc, 2);

  if (part == 0) red[j] = expf(acc);
  __syncthreads();

  // Wave 0: butterfly-reduce the 64 exp values -> row sum in every lane,
  // then coalesced write of the normalized row.
  if (t < 64) {
    float v = red[t];
    float s = v;
#pragma unroll
    for (int o = 1; o < 64; o <<= 1) s += __shfl_xor(s, o);
    out[((size_t)b << 6) + t] = v / s;
  }
}

extern "C" void kernel_launch(void* const* d_in, const int* in_sizes, int n_in,
                              void* d_out, int out_size, void* d_ws, size_t ws_size,
                              hipStream_t stream) {
  const float* x = (const float*)d_in[0];
  const float* a = (const float*)d_in[1];
  float* out = (float*)d_out;
  pairsim_kernel<<<NN * VV, 256, 0, stream>>>(x, a, out);
}

// Round 2
// 11.977 us; speedup vs baseline: 1.4222x; 1.4222x over previous
//
#include <hip/hip_runtime.h>
#include <hip/hip_bf16.h>

// Problem: N=32, T=5, V=64, F=512, t_mid = 2
// xm = x[:, 2, :, :]                         (32, 64, 512)
// tmpS[n,i,j] = exp( sum_f |xm[n,i,f]-xm[n,j,f]| * a[f] )   (symmetric in i,j)
// colsum[n,i] = sum_k tmpS[n,k,i] == sum_k tmpS[n,i,k]  (symmetry -> row-local)
// S[n,i,j] = tmpS[n,i,j] / colsum[n,i]
//
// R2: one block per (n, 4-row i-group). Each thread owns (j, f-part) and
// accumulates against 4 xi rows with vj/va held in registers -> 4x fewer
// redundant global xj reads (268 MB -> 67 MB L2 traffic).

#define NN 32
#define TT 5
#define VV 64
#define FF 512
#define TMID 2
#define IB 4            // i-rows per block

__global__ __launch_bounds__(256) void pairsim_kernel(
    const float* __restrict__ x, const float* __restrict__ a,
    float* __restrict__ out) {
  const int b = blockIdx.x;        // 0 .. NN*(VV/IB)-1 = 511
  const int n = b >> 4;            // b / 16
  const int i0 = (b & 15) * IB;    // first i-row of this block
  const int t = threadIdx.x;       // 0 .. 255

  __shared__ float xi[IB * FF];    // 4 rows of xm[n] (8 KB)
  __shared__ float av[FF];         // weight vector a (2 KB)
  __shared__ float red[IB][VV];    // exp values per (i,j)

  const float* xm = x + ((size_t)n * TT + TMID) * (size_t)VV * FF;

  // Stage xi rows (contiguous 8 KB) + a into LDS, float4-coalesced.
  {
    const float4* src_xi = reinterpret_cast<const float4*>(xm + (size_t)i0 * FF);
    const float4* src_a  = reinterpret_cast<const float4*>(a);
    float4* dst_xi = reinterpret_cast<float4*>(xi);
    float4* dst_a  = reinterpret_cast<float4*>(av);
    for (int idx = t; idx < (IB * FF / 4) + (FF / 4); idx += 256) {
      if (idx < IB * FF / 4) dst_xi[idx] = src_xi[idx];
      else                   dst_a[idx - IB * FF / 4] = src_a[idx - IB * FF / 4];
    }
  }
  __syncthreads();

  const int j = t >> 2;            // 0..63
  const int part = t & 3;          // 0..3 f-partition
  const float* xj = xm + (size_t)j * FF;

  float acc0 = 0.f, acc1 = 0.f, acc2 = 0.f, acc3 = 0.f;
#pragma unroll
  for (int k = 0; k < 32; ++k) {
    const int f = k * 16 + part * 4;   // 4-lane group covers contiguous 64B
    float4 vj = *reinterpret_cast<const float4*>(xj + f);
    float4 va = *reinterpret_cast<const float4*>(av + f);
    float4 v0 = *reinterpret_cast<const float4*>(xi + 0 * FF + f);
    float4 v1 = *reinterpret_cast<const float4*>(xi + 1 * FF + f);
    float4 v2 = *reinterpret_cast<const float4*>(xi + 2 * FF + f);
    float4 v3 = *reinterpret_cast<const float4*>(xi + 3 * FF + f);
    acc0 = fmaf(fabsf(v0.x - vj.x), va.x, acc0);
    acc0 = fmaf(fabsf(v0.y - vj.y), va.y, acc0);
    acc0 = fmaf(fabsf(v0.z - vj.z), va.z, acc0);
    acc0 = fmaf(fabsf(v0.w - vj.w), va.w, acc0);
    acc1 = fmaf(fabsf(v1.x - vj.x), va.x, acc1);
    acc1 = fmaf(fabsf(v1.y - vj.y), va.y, acc1);
    acc1 = fmaf(fabsf(v1.z - vj.z), va.z, acc1);
    acc1 = fmaf(fabsf(v1.w - vj.w), va.w, acc1);
    acc2 = fmaf(fabsf(v2.x - vj.x), va.x, acc2);
    acc2 = fmaf(fabsf(v2.y - vj.y), va.y, acc2);
    acc2 = fmaf(fabsf(v2.z - vj.z), va.z, acc2);
    acc2 = fmaf(fabsf(v2.w - vj.w), va.w, acc2);
    acc3 = fmaf(fabsf(v3.x - vj.x), va.x, acc3);
    acc3 = fmaf(fabsf(v3.y - vj.y), va.y, acc3);
    acc3 = fmaf(fabsf(v3.z - vj.z), va.z, acc3);
    acc3 = fmaf(fabsf(v3.w - vj.w), va.w, acc3);
  }
  // Fold the 4 f-partitions (lanes j*4 .. j*4+3).
  acc0 += __shfl_xor(acc0, 1); acc0 += __shfl_xor(acc0, 2);
  acc1 += __shfl_xor(acc1, 1); acc1 += __shfl_xor(acc1, 2);
  acc2 += __shfl_xor(acc2, 1); acc2 += __shfl_xor(acc2, 2);
  acc3 += __shfl_xor(acc3, 1); acc3 += __shfl_xor(acc3, 2);

  if (part == 0) {
    red[0][j] = expf(acc0);
    red[1][j] = expf(acc1);
    red[2][j] = expf(acc2);
    red[3][j] = expf(acc3);
  }
  __syncthreads();

  // 4 waves, one per i-row: butterfly row-sum, then coalesced 256B row write.
  {
    const int w = t >> 6;          // 0..3 -> i-row
    const int lane = t & 63;       // j
    float v = red[w][lane];
    float s = v;
#pragma unroll
    for (int o = 1; o < 64; o <<= 1) s += __shfl_xor(s, o);
    out[(((size_t)n * VV + i0 + w) << 6) + lane] = v / s;
  }
}

extern "C" void kernel_launch(void* const* d_in, const int* in_sizes, int n_in,
                              void* d_out, int out_size, void* d_ws, size_t ws_size,
                              hipStream_t stream) {
  const float* x = (const float*)d_in[0];
  const float* a = (const float*)d_in[1];
  float* out = (float*)d_out;
  pairsim_kernel<<<NN * (VV / IB), 256, 0, stream>>>(x, a, out);
}